// Round 9
// baseline (232.970 us; speedup 1.0000x reference)
//
#include <hip/hip_runtime.h>
#include <cstdint>
#include <cmath>

// Problem constants (fixed by setup_inputs)
#define NROWS 32768
#define HD    1024
#define NMOT  128
#define NCLS  16
#define KSEL  32
#define EPSV  1e-4f

typedef __attribute__((ext_vector_type(4))) float  f32x4;
typedef __attribute__((ext_vector_type(8))) __bf16 bf16x8;
typedef __attribute__((ext_vector_type(4))) __bf16 bf16x4;
typedef unsigned long long u64;

// ---- workspace layout (in float slots) ----
// wsf[0..256)          : lossP[256] — per-GEMM-block loss partials
// wsf[512..640)        : mn[128]  — motif squared norms
// wsf[1024..66560)     : mvbf — mv converted to bf16 (128x1024)
// wsf[66560..197632)   : s1k[128][512] u64 — stage-1 top-32 keys
// wsf[197632..459776)  : cd[32768][8] — per-row dist to its 8 same-class motifs
#define WS_LP   0
#define WS_MN   512
#define WS_MVBF 1024
#define WS_S1K  66560
#define WS_CD   197632
#define CAPC    256     // per-(class,2048-row-chunk) candidate cap

static __device__ __forceinline__ float dot4(float4 v) {
    return v.x * v.x + v.y * v.y + v.z * v.z + v.w * v.w;
}
static __device__ __forceinline__ float dot4v(f32x4 v) {
    return v[0] * v[0] + v[1] * v[1] + v[2] * v[2] + v[3] * v[3];
}

static __device__ __forceinline__ bf16x4 cvt4(float4 v) {
    bf16x4 t;
    t[0] = (__bf16)v.x; t[1] = (__bf16)v.y; t[2] = (__bf16)v.z; t[3] = (__bf16)v.w;
    return t;
}

static __device__ __forceinline__ bf16x8 cvt8v(f32x4 a, f32x4 b) {
    bf16x8 t;
    t[0] = (__bf16)a[0]; t[1] = (__bf16)a[1]; t[2] = (__bf16)a[2]; t[3] = (__bf16)a[3];
    t[4] = (__bf16)b[0]; t[5] = (__bf16)b[1]; t[6] = (__bf16)b[2]; t[7] = (__bf16)b[3];
    return t;
}

// async 16B global->LDS (DMA; LDS dest = wave-uniform base, HW adds lane*16)
static __device__ __forceinline__ void gl16(const void* g, void* l) {
    __builtin_amdgcn_global_load_lds(
        (const __attribute__((address_space(1))) void*)g,
        (__attribute__((address_space(3))) void*)l, 16, 0, 0);
}

// unsinkable A-load: volatile asm global_load_dwordx4 with literal offset
#define LOADA(dst, base, imm)                                        \
    asm volatile("global_load_dwordx4 %0, %1, off offset:%2"         \
                 : "=&v"(dst) : "v"(base), "n"(imm))

#define WAITN(n) asm volatile("s_waitcnt vmcnt(" #n ")" ::: "memory")

// packed key: ascending u64 order == (value descending, index ascending)
static __device__ __forceinline__ u64 pack_key(float v, int idx) {
    unsigned int b = __float_as_uint(v);
    unsigned int mo = (b & 0x80000000u) ? ~b : (b | 0x80000000u); // ascending map
    unsigned int khi = ~mo;                                      // descending
    return ((u64)khi << 32) | (unsigned int)idx;
}

// ---------------------------------------------------------------------------
// Kernel 0: prep — mv -> bf16 copy + motif squared norms. 128 blocks.
// ---------------------------------------------------------------------------
__global__ __launch_bounds__(256) void prep_k(const float* __restrict__ mv,
                                              float* __restrict__ mn,
                                              __bf16* __restrict__ mvbf) {
    const int b = blockIdx.x;
    const int tid = threadIdx.x;
    const int k = tid * 4;               // 256 threads x 4 = 1024 = HD
    float4 v = *(const float4*)&mv[(size_t)b * HD + k];
    *(bf16x4*)&mvbf[(size_t)b * HD + k] = cvt4(v);
    float s = dot4(v);
#pragma unroll
    for (int o = 1; o < 64; o <<= 1) s += __shfl_xor(s, o, 64);
    __shared__ float red[4];
    if ((tid & 63) == 0) red[tid >> 6] = s;
    __syncthreads();
    if (tid == 0) mn[b] = red[0] + red[1] + red[2] + red[3];
}

// ---------------------------------------------------------------------------
// Kernel 1: z-read-ONCE streaming bf16-MFMA GEMM (z @ M^T), full 128-motif
// width per block, k-chunked double-buffered B.
//  - grid 256 x 512 threads: block = rows rg*128..+127; wave owns 16 rows,
//    ALL 128 cols (acc = 8 x f32x4). z traffic = 134 MB total (1x), vs R8's
//    268 MB (2x) — the measured-constant ~64 µs was BW at 2x traffic.
//  - B (mvbf) staged per k-chunk (128 motifs x 256 k = 64 KB) into a 2-buf
//    LDS ring via global_load_lds DMA, issued at chunk start, consumed next
//    chunk. 3 chunk-boundary barriers use raw s_barrier + lgkmcnt(0) ONLY —
//    the A-ring and next-chunk DMA stay in flight (never vmcnt(0) mid-loop).
//  - A loads: asm volatile global_load_dwordx4 ring, depth 4 slabs.
//    vmcnt derivation (ops issued after the target slab's 2 loads):
//    steady (kc<3): m<4 -> 6 older-A-after + 8 DMA = 14; m>=4 -> 6.
//    last chunk: 6,6,6,6,6,4,2,0.  Prologue: vmcnt(6) = 8 DMA + slab0.
//  - epilogue: full per-row pm/ns in-register (R6-verified), cd write,
//    per-block loss partial lossP[256].
// ---------------------------------------------------------------------------
#define BK 32
#define NS 32          // global k-slabs
#define SPC 8          // slabs per chunk; 4 chunks of 256 k

__global__ __launch_bounds__(512, 1) void gemm_fused(
    const float* __restrict__ z, const __bf16* __restrict__ mvbf,
    const float* __restrict__ mn, float* __restrict__ cd,
    const int* __restrict__ y, float* __restrict__ lossP) {
    __shared__ __align__(16) __bf16 Bs[2][32768];   // 2 x 64 KB k-chunk ring
    __shared__ float redw[8];

    const int tid  = threadIdx.x;
    const int lane = tid & 63;
    const int wid  = tid >> 6;     // 0..7
    const int l15  = lane & 15;
    const int quad = lane >> 4;
    const int rg   = blockIdx.x;   // 0..255
    const int myrow = rg * 128 + wid * 16 + l15;

    const float* zb = z + (size_t)myrow * HD + quad * 8;

    // B DMA: group c = wid*8 + i holds granule (slab-in-chunk s=wid, n-tile
    // j=i): B[i*16+l15][kc*256 + wid*32 + quad*8 .. +8) -> Bs[buf]+c*1024
    // (wave-uniform dest; HW adds lane*16).
    char* bs0 = (char*)Bs[0];
    char* bs1 = (char*)Bs[1];

    // ---- prologue: DMA chunk 0 -> buf0, A slabs 0..3 ----
#pragma unroll
    for (int i = 0; i < 8; ++i)
        gl16(mvbf + (size_t)(i * 16 + l15) * HD + wid * 32 + quad * 8,
             bs0 + (wid * 8 + i) * 1024);

    f32x4 ra[4][2];
#pragma unroll
    for (int s = 0; s < 4; ++s) {
        LOADA(ra[s][0], zb, s * 128);
        LOADA(ra[s][1], zb, s * 128 + 16);
    }
    WAITN(6);                       // 8 DMA + A slab0 retired
    __builtin_amdgcn_sched_barrier(0);
    __builtin_amdgcn_s_barrier();   // all waves' chunk-0 staging landed
    asm volatile("" ::: "memory");

    f32x4 acc[8];
#pragma unroll
    for (int j = 0; j < 8; ++j) acc[j] = (f32x4){0.f, 0.f, 0.f, 0.f};
    float zsq = 0.f;

#pragma unroll
    for (int kc = 0; kc < 4; ++kc) {
        const char* bsc = ((kc & 1) ? bs1 : bs0) + lane * 16;
        // issue DMA for chunk kc+1 into the other buffer
        if (kc + 1 < 4) {
            char* bsn = (((kc + 1) & 1) ? bs1 : bs0);
#pragma unroll
            for (int i = 0; i < 8; ++i)
                gl16(mvbf + (size_t)(i * 16 + l15) * HD + (kc + 1) * 256 +
                         wid * 32 + quad * 8,
                     bsn + (wid * 8 + i) * 1024);
        }
#pragma unroll
        for (int m = 0; m < SPC; ++m) {
            const int kt = kc * SPC + m;
            // counted wait: target slab's loads retired; ring + DMA in flight
            if (kc < 3) {
                if (m < 4) WAITN(14); else WAITN(6);
            } else {
                if (m <= 4) WAITN(6);
                else if (m == 5) WAITN(4);
                else if (m == 6) WAITN(2);
                else WAITN(0);
            }
            __builtin_amdgcn_sched_barrier(0);

            // B fragments for slab kt (granule (m*8+j))
            bf16x8 bfr[8];
#pragma unroll
            for (int j = 0; j < 8; ++j)
                bfr[j] = *(const bf16x8*)(bsc + (m * 8 + j) * 1024);

            // A: consume slab kt, refill ring slot with slab kt+4
            const int sl = kt & 3;
            zsq += dot4v(ra[sl][0]) + dot4v(ra[sl][1]);
            bf16x8 af = cvt8v(ra[sl][0], ra[sl][1]);
            if (kt + 4 < NS) {
                LOADA(ra[sl][0], zb, (kt + 4) * 128);
                LOADA(ra[sl][1], zb, (kt + 4) * 128 + 16);
            }
#pragma unroll
            for (int j = 0; j < 8; ++j)
                acc[j] = __builtin_amdgcn_mfma_f32_16x16x32_bf16(
                    af, bfr[j], acc[j], 0, 0, 0);
        }
        // chunk boundary: LDS reads drained, VMEM pipeline kept alive
        if (kc < 3) {
            asm volatile("s_waitcnt lgkmcnt(0)" ::: "memory");
            __builtin_amdgcn_s_barrier();
            asm volatile("" ::: "memory");
            __builtin_amdgcn_sched_barrier(0);
        }
    }

    // ---- epilogue: in-register (R6-verified) ----
    zsq += __shfl_xor(zsq, 16, 64);
    zsq += __shfl_xor(zsq, 32, 64);   // ||z||^2 of row (wid*16+l15)
    const int yv = y[myrow];
    float mcv[8];
#pragma unroll
    for (int j = 0; j < 8; ++j) mcv[j] = mn[j * 16 + l15];

    float znv[4]; int rcls[4];
#pragma unroll
    for (int reg = 0; reg < 4; ++reg) {
        znv[reg]  = __shfl(zsq, quad * 4 + reg, 64);
        rcls[reg] = __shfl(yv,  quad * 4 + reg, 64);
    }
    float pm[4], ns[4];
#pragma unroll
    for (int reg = 0; reg < 4; ++reg) { pm[reg] = 0.f; ns[reg] = 0.f; }

    // C/D layout: col = lane&15 (within n-tile j), row = quad*4+reg [verified]
#pragma unroll
    for (int j = 0; j < 8; ++j) {
        const int c = j * 16 + l15;
        const float mc = mcv[j];
        const int ccls = c >> 3;
#pragma unroll
        for (int reg = 0; reg < 4; ++reg) {
            float d = znv[reg] + mc - 2.f * acc[j][reg];
            float r = (d + 1.0f) * __builtin_amdgcn_rcpf(d + EPSV);
            float r2 = r * r;
            float s = r2 * r2 * r;   // ratio^5 == exp(log(ratio)/0.2)
            if (ccls == rcls[reg]) {
                pm[reg] = fmaxf(pm[reg], s);
                const int row = rg * 128 + wid * 16 + quad * 4 + reg;
                cd[(size_t)row * 8 + (c & 7)] = d;
            } else {
                ns[reg] += s;
            }
        }
    }
#pragma unroll
    for (int o = 1; o < 16; o <<= 1)
#pragma unroll
        for (int reg = 0; reg < 4; ++reg) {
            pm[reg] = fmaxf(pm[reg], __shfl_xor(pm[reg], o, 64));
            ns[reg] += __shfl_xor(ns[reg], o, 64);
        }
    float li = 0.f;
    if (l15 == 0) {
#pragma unroll
        for (int reg = 0; reg < 4; ++reg)
            li += logf((ns[reg] + pm[reg]) / pm[reg]);  // = -log(pos/(neg+pos))
    }
    li += __shfl_xor(li, 16, 64);
    li += __shfl_xor(li, 32, 64);
    if (lane == 0) redw[wid] = li;
    __syncthreads();
    if (tid == 0) {
        float t = 0.f;
#pragma unroll
        for (int w = 0; w < 8; ++w) t += redw[w];
        lossP[blockIdx.x] = t;
    }
}

// ---------------------------------------------------------------------------
// Kernel 2: stage-1 top-32. One block per (motif, 2048-row chunk) = 2048
// blocks. Inline ballot-scan of y builds the candidate list (<=256), gathers
// cd, packs keys, bitonic-256 sorts (== value desc, idx asc), emits top-32.
// ---------------------------------------------------------------------------
__global__ __launch_bounds__(256) void sel1_k(const int* __restrict__ y,
                                              const float* __restrict__ cd,
                                              u64* __restrict__ s1k) {
    __shared__ u64 keys[256];
    __shared__ int clist[CAPC];
    __shared__ int cnt;

    const int bid = blockIdx.x;
    const int j = bid >> 4, chunk = bid & 15;
    const int cls = j >> 3, m8 = j & 7;
    const int tid = threadIdx.x;
    const int lane = tid & 63;

    if (tid == 0) cnt = 0;
    __syncthreads();
    const int base = chunk * 2048;
#pragma unroll
    for (int t = 0; t < 8; ++t) {
        const int i = base + t * 256 + tid;
        const bool pred = (y[i] == cls);
        const u64 m = __ballot(pred);
        int wbase = 0;
        if (lane == 0 && m) wbase = atomicAdd(&cnt, (int)__popcll(m));
        wbase = __shfl(wbase, 0, 64);
        if (pred) {
            const int p = wbase + (int)__popcll(m & ((1ull << lane) - 1ull));
            if (p < CAPC) clist[p] = i;
        }
    }
    __syncthreads();
    const int n = cnt < CAPC ? cnt : CAPC;

    u64 key = ~0ull;
    if (tid < n) {
        const int idx = clist[tid];
        key = pack_key(cd[(size_t)idx * 8 + m8], idx);
    }
    keys[tid] = key;
    __syncthreads();

    for (int k = 2; k <= 256; k <<= 1) {
        for (int jj = k >> 1; jj > 0; jj >>= 1) {
            if (tid < 128) {
                const int i  = ((tid & ~(jj - 1)) << 1) | (tid & (jj - 1));
                const int ix = i | jj;
                const u64 A = keys[i], B = keys[ix];
                const bool up = ((i & k) == 0);
                if ((A > B) == up) { keys[i] = B; keys[ix] = A; }
            }
            __syncthreads();
        }
    }
    if (tid < KSEL) s1k[(size_t)j * 512 + chunk * KSEL + tid] = keys[tid];
}

// ---------------------------------------------------------------------------
// Kernel 3: merge 16x32 stage-1 keys -> global top-32 (bitonic-512, redundant
// per column-quarter), gather-mean of selected z rows, tau-blend, write.
// 512 blocks: (motif j = b>>2, column quarter q = b&3). Block 0 also sums the
// 256 loss partials -> out[0].
// ---------------------------------------------------------------------------
__global__ __launch_bounds__(256) void merge_k(
    const float* __restrict__ z, const float* __restrict__ mv,
    const u64* __restrict__ s1k, const float* __restrict__ lossP,
    float* __restrict__ out) {
    __shared__ u64 keys[512];
    __shared__ int sel[KSEL];
    __shared__ float redf[4];

    const int b = blockIdx.x;
    const int j = b >> 2, q = b & 3;
    const int tid = threadIdx.x;
    const int lane = tid & 63;
    const int wave = tid >> 6;

    if (b == 0) {
        float s = lossP[tid];
#pragma unroll
        for (int o = 1; o < 64; o <<= 1) s += __shfl_xor(s, o, 64);
        if (lane == 0) redf[wave] = s;
        __syncthreads();
        if (tid == 0)
            out[0] = (redf[0] + redf[1] + redf[2] + redf[3]) * (1.0f / NROWS);
    }

    keys[tid]       = s1k[(size_t)j * 512 + tid];
    keys[tid + 256] = s1k[(size_t)j * 512 + 256 + tid];
    __syncthreads();

    for (int k = 2; k <= 512; k <<= 1) {
        for (int jj = k >> 1; jj > 0; jj >>= 1) {
            const int i  = ((tid & ~(jj - 1)) << 1) | (tid & (jj - 1));
            const int ix = i | jj;
            const u64 A = keys[i], B = keys[ix];
            const bool up = ((i & k) == 0);
            if ((A > B) == up) { keys[i] = B; keys[ix] = A; }
            __syncthreads();
        }
    }
    if (tid < KSEL) sel[tid] = (int)(keys[tid] & 0xFFFFFFFFu);
    __syncthreads();

    const int h = q * 256 + tid;
    float s = 0.f;
#pragma unroll 8
    for (int r = 0; r < KSEL; ++r) s += z[(size_t)sel[r] * HD + h];
    out[1 + (size_t)j * HD + h] =
        0.99f * mv[(size_t)j * HD + h] + 0.01f * (s * (1.0f / KSEL));
}

// ---------------------------------------------------------------------------
extern "C" void kernel_launch(void* const* d_in, const int* in_sizes, int n_in,
                              void* d_out, int out_size, void* d_ws, size_t ws_size,
                              hipStream_t stream) {
    const float* z  = (const float*)d_in[0];
    const float* mv = (const float*)d_in[1];
    const int*   y  = (const int*)d_in[2];
    float* out = (float*)d_out;
    float* wsf = (float*)d_ws;
    float*  lossP = wsf + WS_LP;
    float*  mn    = wsf + WS_MN;
    __bf16* mvbf  = (__bf16*)(wsf + WS_MVBF);
    u64*    s1k   = (u64*)(wsf + WS_S1K);
    float*  cd    = wsf + WS_CD;

    hipLaunchKernelGGL(prep_k,     dim3(NMOT),      dim3(256), 0, stream,
                       mv, mn, mvbf);
    hipLaunchKernelGGL(gemm_fused, dim3(256),       dim3(512), 0, stream,
                       z, mvbf, mn, cd, y, lossP);
    hipLaunchKernelGGL(sel1_k,     dim3(NMOT * 16), dim3(256), 0, stream,
                       y, cd, s1k);
    hipLaunchKernelGGL(merge_k,    dim3(NMOT * 4),  dim3(256), 0, stream,
                       z, mv, s1k, lossP, out);
}